// Round 2
// baseline (365.954 us; speedup 1.0000x reference)
//
#include <hip/hip_runtime.h>
#include <hip/hip_bf16.h>

// Problem constants
#define B_   4
#define S_   2048
#define H_   16
#define D_   64
#define DM_  1024
#define BH_  (B_ * H_)

// log2(e)/32 : softmax uses score/(D/2)=score/32, computed via exp2
#define LOG2E_D32 0.04508422002778011f

typedef unsigned short u16;
typedef u16  u16x4  __attribute__((ext_vector_type(4)));
typedef u16  u16x8  __attribute__((ext_vector_type(8)));
typedef float f32x4 __attribute__((ext_vector_type(4)));
typedef __bf16 bf16x8 __attribute__((ext_vector_type(8)));

__device__ __forceinline__ u16 f2bf(float f) {
    __hip_bfloat16 h = __float2bfloat16(f);
    return *reinterpret_cast<u16*>(&h);
}
// 8 consecutive fp32 -> bf16x8 fragment
__device__ __forceinline__ bf16x8 cvt8(const float* p) {
    float4 a = *(const float4*)p;
    float4 b = *(const float4*)(p + 4);
    u16x8 r;
    r[0] = f2bf(a.x); r[1] = f2bf(a.y); r[2] = f2bf(a.z); r[3] = f2bf(a.w);
    r[4] = f2bf(b.x); r[5] = f2bf(b.y); r[6] = f2bf(b.z); r[7] = f2bf(b.w);
    union { u16x8 u; bf16x8 h; } cv; cv.u = r; return cv.h;
}
// async global->LDS, 16B per lane; LDS dest = wave-uniform base + lane*16
__device__ __forceinline__ void load_lds16(const u16* g, u16* l) {
    __builtin_amdgcn_global_load_lds(
        (const __attribute__((address_space(1))) unsigned int*)g,
        (__attribute__((address_space(3))) unsigned int*)l, 16, 0, 0);
}
#define MFMA16(a, b, c) __builtin_amdgcn_mfma_f32_16x16x32_bf16(a, b, c, 0, 0, 0)

// ---------------------------------------------------------------------------
// Kernel 0: fp32 -> bf16 convert (for Wo), 4 elems/thread
// ---------------------------------------------------------------------------
__global__ __launch_bounds__(256) void cvt_kernel(
    const float* __restrict__ in, u16* __restrict__ outp)
{
    int i = (blockIdx.x * 256 + threadIdx.x) * 4;
    float4 v = *(const float4*)(in + i);
    u16x4 o; o[0] = f2bf(v.x); o[1] = f2bf(v.y); o[2] = f2bf(v.z); o[3] = f2bf(v.w);
    *(u16x4*)(outp + i) = o;
}

// ---------------------------------------------------------------------------
// Kernel 1: per-head QKV projection (fp32 in, bf16 out).
//   z=0: Q -> Qp [bh][s][d]   z=1: K -> Kp [bh][s][d]   z=2: V -> Vp [bh][d][s]
// Block: 256 thr, handles 64 tokens of one (b,h). Wave w: 16 tokens (m-tile).
// ---------------------------------------------------------------------------
__global__ __launch_bounds__(256) void proj_kernel(
    const float* __restrict__ xq, const float* __restrict__ xk, const float* __restrict__ xv,
    const float* __restrict__ Wq, const float* __restrict__ bq,
    const float* __restrict__ Wk, const float* __restrict__ bk,
    const float* __restrict__ Wv, const float* __restrict__ bv,
    u16* __restrict__ Qp, u16* __restrict__ Kp, u16* __restrict__ Vp)
{
    __shared__ u16 vt[64 * 72];   // V-transpose staging, row stride 72 (16B-aligned)

    const int z     = blockIdx.z;
    const float* x    = (z == 0) ? xq : (z == 1) ? xk : xv;
    const float* W    = (z == 0) ? Wq : (z == 1) ? Wk : Wv;
    const float* bias = (z == 0) ? bq : (z == 1) ? bk : bv;

    const int tid = threadIdx.x, w = tid >> 6, lane = tid & 63;
    const int l15 = lane & 15, quad = lane >> 4;
    const int bh = blockIdx.y, b = bh >> 4, h = bh & 15;
    const int s0 = blockIdx.x * 64;

    // A frags: 16 tokens (rows = l15), K=64 in 2 steps of 32
    const int srow = s0 + w * 16 + l15;
    const float* xp = x + ((size_t)(b * S_ + srow) * H_ + h) * D_;
    bf16x8 a0 = cvt8(xp + quad * 8);
    bf16x8 a1 = cvt8(xp + 32 + quad * 8);

    f32x4 acc[4];
#pragma unroll
    for (int nt = 0; nt < 4; ++nt) {
        const float* wp = W + (nt * 16 + l15) * D_;
        f32x4 c = {0.f, 0.f, 0.f, 0.f};
        c = MFMA16(a0, cvt8(wp + quad * 8), c);
        c = MFMA16(a1, cvt8(wp + 32 + quad * 8), c);
        acc[nt] = c;
    }

    if (z < 2) {
        u16* out = (z == 0) ? Qp : Kp;
#pragma unroll
        for (int nt = 0; nt < 4; ++nt) {
            float bs = bias[nt * 16 + l15];
#pragma unroll
            for (int r = 0; r < 4; ++r) {
                int s = s0 + w * 16 + quad * 4 + r;     // C row = quad*4+reg
                out[((size_t)bh * S_ + s) * D_ + nt * 16 + l15] = f2bf(acc[nt][r] + bs);
            }
        }
    } else {
        // V: transpose [s][d] -> [d][s] through LDS (XOR-swizzled 8-elem chunks)
#pragma unroll
        for (int nt = 0; nt < 4; ++nt) {
            float bs = bias[nt * 16 + l15];
            u16x4 pu;
#pragma unroll
            for (int r = 0; r < 4; ++r) pu[r] = f2bf(acc[nt][r] + bs);
            int d  = nt * 16 + l15;                 // row of vt
            int cc = w * 16 + quad * 4;             // s-col base (4 consecutive)
            int ch = (cc >> 3) ^ (d & 7);           // swizzled chunk
            *(u16x4*)&vt[d * 72 + ch * 8 + (cc & 7)] = pu;
        }
        __syncthreads();
        int d  = tid >> 2;
        int cb = (tid & 3) * 16;
        size_t gbase = ((size_t)bh * 64 + d) * S_ + s0;
#pragma unroll
        for (int u = 0; u < 2; ++u) {
            int ch  = (cb >> 3) + u;
            int ch2 = ch ^ (d & 7);
            u16x8 val = *(const u16x8*)&vt[d * 72 + ch2 * 8];
            *(u16x8*)(Vp + gbase + ch * 8) = val;
        }
    }
}

// ---------------------------------------------------------------------------
// Kernel 2: flash attention per (b,h). Block: 256 thr, 128 q-rows (32/wave).
// Computes S^T = K Q^T (C-layout: q=lane&15, kseq=quad*4+reg), online softmax,
// O^T = V^T P^T. KV tiles of 64 staged via global_load_lds, XOR-swizzled.
// ---------------------------------------------------------------------------
__global__ __launch_bounds__(256) void attn_kernel(
    const u16* __restrict__ Qp, const u16* __restrict__ Kp,
    const u16* __restrict__ Vp, u16* __restrict__ Ao)
{
    __shared__ u16 kt[64 * 64];        // K tile  [kseq][d], swizzled chunks
    __shared__ u16 vt[64 * 64];        // V^T tile [d][kseq], swizzled chunks
    __shared__ u16 pt[4][32 * 72];     // per-wave P [q][kseq], row stride 72

    const int tid = threadIdx.x, w = tid >> 6, lane = tid & 63;
    const int l15 = lane & 15, quad = lane >> 4;
    const int bh = blockIdx.y, b = bh >> 4, h = bh & 15;
    const int qbase = blockIdx.x * 128 + w * 32;

    // Q b-frags (B operand of S^T): lane holds Q[q=l15+nt*16][d=quad*8+j]
    bf16x8 qf[2][2];
#pragma unroll
    for (int nt = 0; nt < 2; ++nt) {
        const bf16x8* qp = (const bf16x8*)(Qp + ((size_t)bh * S_ + qbase + nt * 16 + l15) * D_);
        qf[nt][0] = qp[quad];
        qf[nt][1] = qp[4 + quad];
    }

    f32x4 ot[4][2];   // O^T accum: [d-tile][q-tile]
#pragma unroll
    for (int mt = 0; mt < 4; ++mt)
#pragma unroll
        for (int nt = 0; nt < 2; ++nt) ot[mt][nt] = (f32x4){0.f, 0.f, 0.f, 0.f};
    float mx[2] = {-__builtin_inff(), -__builtin_inff()};
    float li[2] = {0.f, 0.f};

    const size_t krow = (size_t)bh * S_;
    const size_t vrow = (size_t)bh * 64;

    for (int it = 0; it < S_ / 64; ++it) {
        const int k0 = it * 64;
        __syncthreads();   // prev tile fully consumed
#pragma unroll
        for (int c = 0; c < 4; ++c) {
            int ci = w * 4 + c;                  // 0..15 across block
            if (ci < 8) {                        // K tile: 512 chunks
                int chunk = ci * 64 + lane;
                int r = chunk >> 3, j = chunk & 7;
                load_lds16(Kp + (krow + k0 + r) * D_ + ((j ^ (r & 7)) << 3),
                           &kt[ci * 512]);
            } else {                             // V^T tile
                int ci2 = ci - 8;
                int chunk = ci2 * 64 + lane;
                int r = chunk >> 3, j = chunk & 7;
                load_lds16(Vp + (vrow + r) * S_ + k0 + ((j ^ (r & 7)) << 3),
                           &vt[ci2 * 512]);
            }
        }
        __syncthreads();   // drains vmcnt -> tiles visible

        // ---- S^T = K Q^T  (m=kseq, n=q, k=d) ----
        f32x4 st[4][2];
#pragma unroll
        for (int mt = 0; mt < 4; ++mt) {
            int rk = mt * 16 + l15;
            bf16x8 ak0 = *(const bf16x8*)&kt[rk * 64 + ((quad       ^ (rk & 7)) << 3)];
            bf16x8 ak1 = *(const bf16x8*)&kt[rk * 64 + (((4 + quad) ^ (rk & 7)) << 3)];
#pragma unroll
            for (int nt = 0; nt < 2; ++nt) {
                f32x4 c = {0.f, 0.f, 0.f, 0.f};
                c = MFMA16(ak0, qf[nt][0], c);
                c = MFMA16(ak1, qf[nt][1], c);
                st[mt][nt] = c;
            }
        }

        // ---- online softmax (row = q = l15, per-lane scalar stats) ----
#pragma unroll
        for (int nt = 0; nt < 2; ++nt) {
            float rm = mx[nt];
#pragma unroll
            for (int mt = 0; mt < 4; ++mt)
#pragma unroll
                for (int r = 0; r < 4; ++r) {
                    float y = st[mt][nt][r] * LOG2E_D32;
                    st[mt][nt][r] = y;
                    rm = fmaxf(rm, y);
                }
            rm = fmaxf(rm, __shfl_xor(rm, 16));
            rm = fmaxf(rm, __shfl_xor(rm, 32));
            float alpha = __builtin_amdgcn_exp2f(mx[nt] - rm);
            float ls = 0.f;
#pragma unroll
            for (int mt = 0; mt < 4; ++mt) {
                u16x4 pu;
#pragma unroll
                for (int r = 0; r < 4; ++r) {
                    float p = __builtin_amdgcn_exp2f(st[mt][nt][r] - rm);
                    ls += p;
                    pu[r] = f2bf(p);
                }
                // P[q][kseq]: 4 consecutive kseq per lane -> packed b64 write
                *(u16x4*)&pt[w][(nt * 16 + l15) * 72 + mt * 16 + quad * 4] = pu;
            }
            ls += __shfl_xor(ls, 16);
            ls += __shfl_xor(ls, 32);
            li[nt] = li[nt] * alpha + ls;
            mx[nt] = rm;
#pragma unroll
            for (int mt = 0; mt < 4; ++mt)
#pragma unroll
                for (int r = 0; r < 4; ++r) ot[mt][nt][r] *= alpha;
        }

        // ---- O^T += V^T P^T  (m=d, n=q, k=kseq) ----
#pragma unroll
        for (int ks = 0; ks < 2; ++ks) {
            bf16x8 bp[2];
#pragma unroll
            for (int nt = 0; nt < 2; ++nt)
                bp[nt] = *(const bf16x8*)&pt[w][(nt * 16 + l15) * 72 + ks * 32 + quad * 8];
#pragma unroll
            for (int mt = 0; mt < 4; ++mt) {
                int rv = mt * 16 + l15;
                bf16x8 av = *(const bf16x8*)&vt[rv * 64 + (((ks * 4 + quad) ^ (rv & 7)) << 3)];
#pragma unroll
                for (int nt = 0; nt < 2; ++nt)
                    ot[mt][nt] = MFMA16(av, bp[nt], ot[mt][nt]);
            }
        }
    }

    // ---- epilogue: O^T/l -> Ao [b][s][h*64+d], packed 8B stores ----
#pragma unroll
    for (int nt = 0; nt < 2; ++nt) {
        float inv = 1.f / li[nt];
        int qrow = qbase + nt * 16 + l15;
        u16* orow = Ao + (((size_t)b * S_ + qrow) * H_ + h) * D_;
#pragma unroll
        for (int mt = 0; mt < 4; ++mt) {
            u16x4 o;
#pragma unroll
            for (int r = 0; r < 4; ++r) o[r] = f2bf(ot[mt][nt][r] * inv);
            *(u16x4*)(orow + mt * 16 + quad * 4) = o;
        }
    }
}

// ---------------------------------------------------------------------------
// Kernel 3: output projection C = Ao @ Wo^T + bo (bf16 ws in, fp32 out).
// M=8192, N=1024, K=1024. 128x128 tile, BK=64, 4 waves (2x2 of 64x64).
// ---------------------------------------------------------------------------
__global__ __launch_bounds__(256) void oproj_kernel(
    const u16* __restrict__ A, const u16* __restrict__ Wob,
    const float* __restrict__ bo, float* __restrict__ C)
{
    __shared__ u16 at[128 * 64];
    __shared__ u16 bt[128 * 64];

    const int tid = threadIdx.x, w = tid >> 6, lane = tid & 63;
    const int l15 = lane & 15, quad = lane >> 4;
    const int m0 = blockIdx.y * 128;
    const int n0 = blockIdx.x * 128;
    const int wm = w & 1, wn = w >> 1;

    f32x4 acc[4][4];
#pragma unroll
    for (int mt = 0; mt < 4; ++mt)
#pragma unroll
        for (int nt = 0; nt < 4; ++nt) acc[mt][nt] = (f32x4){0.f, 0.f, 0.f, 0.f};

    for (int kk = 0; kk < DM_ / 64; ++kk) {
        __syncthreads();
#pragma unroll
        for (int c = 0; c < 8; ++c) {
            int ci = w * 8 + c;                  // 0..31
            int t  = ci & 15;
            int chunk = t * 64 + lane;           // 0..1023
            int r = chunk >> 3, j = chunk & 7;
            int col = kk * 64 + ((j ^ (r & 7)) << 3);
            if (ci < 16) load_lds16(A   + (size_t)(m0 + r) * DM_ + col, &at[t * 512]);
            else         load_lds16(Wob + (size_t)(n0 + r) * DM_ + col, &bt[t * 512]);
        }
        __syncthreads();

#pragma unroll
        for (int ks = 0; ks < 2; ++ks) {
            bf16x8 af[4], bf[4];
#pragma unroll
            for (int mt = 0; mt < 4; ++mt) {
                int r = wm * 64 + mt * 16 + l15;
                af[mt] = *(const bf16x8*)&at[r * 64 + (((ks * 4 + quad) ^ (r & 7)) << 3)];
            }
#pragma unroll
            for (int nt = 0; nt < 4; ++nt) {
                int r = wn * 64 + nt * 16 + l15;
                bf[nt] = *(const bf16x8*)&bt[r * 64 + (((ks * 4 + quad) ^ (r & 7)) << 3)];
            }
#pragma unroll
            for (int mt = 0; mt < 4; ++mt)
#pragma unroll
                for (int nt = 0; nt < 4; ++nt)
                    acc[mt][nt] = MFMA16(af[mt], bf[nt], acc[mt][nt]);
        }
    }

#pragma unroll
    for (int nt = 0; nt < 4; ++nt) {
        int ng = n0 + wn * 64 + nt * 16 + l15;
        float bs = bo[ng];
#pragma unroll
        for (int mt = 0; mt < 4; ++mt) {
            int mg = m0 + wm * 64 + mt * 16 + quad * 4;
#pragma unroll
            for (int r = 0; r < 4; ++r)
                C[(size_t)(mg + r) * DM_ + ng] = acc[mt][nt][r] + bs;
        }
    }
}

// ---------------------------------------------------------------------------
extern "C" void kernel_launch(void* const* d_in, const int* in_sizes, int n_in,
                              void* d_out, int out_size, void* d_ws, size_t ws_size,
                              hipStream_t stream)
{
    const float* q   = (const float*)d_in[0];
    const float* k   = (const float*)d_in[1];
    const float* v   = (const float*)d_in[2];
    // d_in[3] = mask (int32) -- reference discards masked_fill result; unused.
    const float* Wq  = (const float*)d_in[4];
    const float* bq  = (const float*)d_in[5];
    const float* Wk  = (const float*)d_in[6];
    const float* bk  = (const float*)d_in[7];
    const float* Wv  = (const float*)d_in[8];
    const float* bv  = (const float*)d_in[9];
    const float* Wo  = (const float*)d_in[10];
    const float* bo  = (const float*)d_in[11];
    float* out = (float*)d_out;

    const size_t TENS = (size_t)B_ * S_ * DM_;   // 8M elems
    u16* Qp  = (u16*)d_ws;         // [bh][s][d]          bf16
    u16* Kp  = Qp + TENS;          // [bh][s][d]          bf16
    u16* Vp  = Kp + TENS;          // [bh][d][s]          bf16 (transposed)
    u16* Ao  = Vp + TENS;          // [b][s][h*d]         bf16
    u16* Wob = Ao + TENS;          // [1024][1024]        bf16

    cvt_kernel<<<dim3((DM_ * DM_) / 1024), 256, 0, stream>>>(Wo, Wob);
    proj_kernel<<<dim3(S_ / 64, BH_, 3), 256, 0, stream>>>(
        q, k, v, Wq, bq, Wk, bk, Wv, bv, Qp, Kp, Vp);
    attn_kernel<<<dim3(S_ / 128, BH_), 256, 0, stream>>>(Qp, Kp, Vp, Ao);
    oproj_kernel<<<dim3(DM_ / 128, (B_ * S_) / 128), 256, 0, stream>>>(Ao, Wob, bo, out);
}